// Round 1
// baseline (565.095 us; speedup 1.0000x reference)
//
#include <hip/hip_runtime.h>
#include <math.h>

#define HIDDEN 768
#define NHEADS 12
#define DHEAD  64
#define NB     8
#define LQ     512
#define LK     1024
#define LN_EPS 1e-12f
#define TS     1032   // bf16 shorts per S row (1024+8): stride 2064 B = 129 x 16B units

typedef __attribute__((ext_vector_type(8))) short short8;
typedef __attribute__((ext_vector_type(4))) float floatx4;

#define GLDS16(gp, lp) __builtin_amdgcn_global_load_lds( \
    (const __attribute__((address_space(1))) void*)(gp), \
    (__attribute__((address_space(3))) void*)(lp), 16, 0, 0)

__device__ __forceinline__ short f2bf(float f) {
    unsigned u = __float_as_uint(f);
    u = u + 0x7FFFu + ((u >> 16) & 1u);   // RNE
    return (short)(u >> 16);
}

__device__ __forceinline__ float bf2f(short s) {
    return __uint_as_float(((unsigned)(unsigned short)s) << 16);
}

// ---------------------------------------------------------------------------
// fp32 -> bf16 elementwise convert (n4 = n/4)
// ---------------------------------------------------------------------------
__global__ __launch_bounds__(256)
void cvt_f32_bf16(const float* __restrict__ in, short* __restrict__ out, int n4)
{
    int i = blockIdx.x * 256 + threadIdx.x;
    if (i >= n4) return;
    float4 v = ((const float4*)in)[i];
    short4 o;
    o.x = f2bf(v.x); o.y = f2bf(v.y); o.z = f2bf(v.z); o.w = f2bf(v.w);
    ((short4*)out)[i] = o;
}

// ---------------------------------------------------------------------------
// bf16 NT MFMA GEMM (128x128 tile, BK=32) - unchanged.
// ---------------------------------------------------------------------------
__global__ __launch_bounds__(256)
void gemm_nt_mfma(const short* __restrict__ A, const short* __restrict__ B,
                  float* __restrict__ Cf, short* __restrict__ Cb,
                  const float* __restrict__ bias, const float* __restrict__ res,
                  int K, int lda, int ldb, int ldc, float alpha)
{
    __shared__ short As[4096];
    __shared__ short Bs[4096];

    int n0 = blockIdx.x * 128;
    int m0 = blockIdx.y * 128;
    int t    = threadIdx.x;
    int lane = t & 63, wave = t >> 6;
    int quad = lane >> 4, l15 = lane & 15;
    int wr = wave >> 1, wc = wave & 1;

    int e0 = t, e1 = 256 + t;
    int r0 = e0 >> 2, c0 = (e0 & 3) ^ ((r0 >> 1) & 3);
    int r1 = e1 >> 2, c1 = (e1 & 3) ^ ((r1 >> 1) & 3);
    const short* Ap0 = A + (size_t)(m0 + r0) * lda + c0 * 8;
    const short* Ap1 = A + (size_t)(m0 + r1) * lda + c1 * 8;
    const short* Bp0 = B + (size_t)(n0 + r0) * ldb + c0 * 8;
    const short* Bp1 = B + (size_t)(n0 + r1) * ldb + c1 * 8;

    int aoff[4], boff[4];
#pragma unroll
    for (int i = 0; i < 4; i++) {
        int ra = wr * 64 + i * 16 + l15;
        aoff[i] = (ra * 4 + (quad ^ ((ra >> 1) & 3))) * 8;
        int rb = wc * 64 + i * 16 + l15;
        boff[i] = (rb * 4 + (quad ^ ((rb >> 1) & 3))) * 8;
    }

    floatx4 acc[4][4] = {};

    for (int k0 = 0; k0 < K; k0 += 32) {
        GLDS16(Ap0, &As[e0 * 8]);
        GLDS16(Ap1, &As[e1 * 8]);
        GLDS16(Bp0, &Bs[e0 * 8]);
        GLDS16(Bp1, &Bs[e1 * 8]);
        Ap0 += 32; Ap1 += 32; Bp0 += 32; Bp1 += 32;
        __syncthreads();

        short8 af[4], bfr[4];
#pragma unroll
        for (int i = 0; i < 4; i++) af[i]  = *(const short8*)&As[aoff[i]];
#pragma unroll
        for (int j = 0; j < 4; j++) bfr[j] = *(const short8*)&Bs[boff[j]];
#pragma unroll
        for (int i = 0; i < 4; i++)
#pragma unroll
            for (int j = 0; j < 4; j++)
                acc[i][j] = __builtin_amdgcn_mfma_f32_16x16x32_bf16(
                    af[i], bfr[j], acc[i][j], 0, 0, 0);
        __syncthreads();
    }

#pragma unroll
    for (int i = 0; i < 4; i++) {
        int mb = m0 + wr * 64 + i * 16 + quad * 4;
#pragma unroll
        for (int j = 0; j < 4; j++) {
            int n = n0 + wc * 64 + j * 16 + l15;
            float bv = bias ? bias[n] : 0.f;
#pragma unroll
            for (int r = 0; r < 4; r++) {
                int m = mb + r;
                float v = alpha * acc[i][j][r] + bv;
                if (res) v += res[(size_t)m * ldc + n];
                if (Cb) Cb[(size_t)m * ldc + n] = f2bf(v);
                else    Cf[(size_t)m * ldc + n] = v;
            }
        }
    }
}

// ---------------------------------------------------------------------------
// Transpose V proj: vb [B, LK, 768] -> vt [bh][64 d][1024 k]
// ---------------------------------------------------------------------------
__global__ __launch_bounds__(256)
void transpose_v(const short* __restrict__ vb, short* __restrict__ vt)
{
    __shared__ short T[256 * 72];   // 36 KB, pad 72 to break bank conflicts
    int kt = blockIdx.x, bh = blockIdx.y;
    int b = bh / 12, h = bh - b * 12;
    int t = threadIdx.x;
    const short* src = vb + ((size_t)b * LK + kt * 256) * HIDDEN + h * DHEAD;
#pragma unroll
    for (int it = 0; it < 8; it++) {
        int s = it * 256 + t;
        int k = s >> 3, c = s & 7;
        *(short8*)&T[k * 72 + c * 8] =
            *(const short8*)&src[(size_t)k * HIDDEN + c * 8];
    }
    __syncthreads();
    short* dst = vt + (size_t)bh * DHEAD * LK + kt * 256;
#pragma unroll
    for (int it = 0; it < 8; it++) {
        int s = it * 256 + t;
        int d = s >> 5, kc = s & 31;
        short8 v;
#pragma unroll
        for (int i = 0; i < 8; i++) v[i] = T[(kc * 8 + i) * 72 + d];
        *(short8*)&dst[(size_t)d * LK + kc * 8] = v;
    }
}

// ---------------------------------------------------------------------------
// Fused attention, barrier-light restructure:
//  - S resident in LDS as bf16 (64.5 KB) -> 2 blocks/CU (was 1)
//  - K and V B-fragments loaded straight from L2 (no LDS staging, no
//    per-chunk barriers; waves fully independent within each phase)
//  - XCD-locality remap: all 16 q-tiles of one (b,h) share one XCD's L2
//  - exp/probs passes use 16B-unit interleave (row stride 129 units, odd)
//    so consecutive lanes spread across all bank groups
// ---------------------------------------------------------------------------
__global__ __launch_bounds__(256)
void fused_attn(const short* __restrict__ qb, const short* __restrict__ kb,
                const short* __restrict__ vt, const float* __restrict__ amask,
                float* __restrict__ probs, short* __restrict__ ctxb)
{
    __shared__ short S[32 * TS];           // 64.5 KB bf16 scores -> exp(s-m)
    __shared__ float mpart[4][32];
    __shared__ float mrow[32], lrow[32];

    // XCD remap: flat dispatch id round-robins XCDs (xcd = flat & 7).
    // Give each XCD a contiguous group of 12 bh (3 MB K+V, fits 4 MiB L2).
    int flat = blockIdx.y * 16 + blockIdx.x;       // 0..1535
    int jj   = flat >> 3;                          // 0..191
    int bh   = (flat & 7) * 12 + jj % 12;
    int qt   = jj / 12;                            // 0..15
    int b = bh / 12, h = bh - b * 12;
    int m0 = qt * 32;

    const short* Qg = qb + ((size_t)b * LQ + m0) * HIDDEN + h * DHEAD;
    const short* Kg = kb + (size_t)b * LK * HIDDEN + h * DHEAD;
    const short* Vg = vt + (size_t)bh * DHEAD * LK;
    const float* Mg = amask + (size_t)b * LK;
    float* Pg = probs + (size_t)bh * LQ * LK + (size_t)m0 * LK;
    short* Cg = ctxb + ((size_t)b * LQ + m0) * HIDDEN + h * DHEAD;

    int t = threadIdx.x;
    int lane = t & 63, w = t >> 6;
    int quad = lane >> 4, l15 = lane & 15;

    // Q fragments straight from global (4 KB/block, L2-resident)
    // A-frag: row = i*16 + l15, k = ks*32 + quad*8 + e
    short8 af[2][2];
#pragma unroll
    for (int i = 0; i < 2; i++)
#pragma unroll
        for (int ks = 0; ks < 2; ks++)
            af[i][ks] = *(const short8*)&Qg[(size_t)(i * 16 + l15) * HIDDEN
                                            + ks * 32 + quad * 8];

    float mx[8];
#pragma unroll
    for (int i = 0; i < 8; i++) mx[i] = -3.0e38f;

    // ====== scores: barrier-free; wave w owns cols kc*64 + w*16 + l15 =====
#pragma unroll 4
    for (int kc = 0; kc < 16; kc++) {
        int n = kc * 64 + w * 16 + l15;
        const short* Kp = Kg + (size_t)n * HIDDEN;
        floatx4 acc[2] = {};
#pragma unroll
        for (int ks = 0; ks < 2; ks++) {
            short8 bfr = *(const short8*)&Kp[ks * 32 + quad * 8];
#pragma unroll
            for (int i = 0; i < 2; i++)
                acc[i] = __builtin_amdgcn_mfma_f32_16x16x32_bf16(
                    af[i][ks], bfr, acc[i], 0, 0, 0);
        }
        float mk = Mg[n];
#pragma unroll
        for (int i = 0; i < 2; i++)
#pragma unroll
            for (int r = 0; r < 4; r++) {
                int m = i * 16 + quad * 4 + r;
                float v = acc[i][r] * 0.125f + mk;
                S[m * TS + n] = f2bf(v);
                mx[i * 4 + r] = fmaxf(mx[i * 4 + r], v);
            }
    }

    // row max: shuffle across l15 (within wave), LDS across waves
#pragma unroll
    for (int d = 1; d < 16; d <<= 1)
#pragma unroll
        for (int i = 0; i < 8; i++)
            mx[i] = fmaxf(mx[i], __shfl_xor(mx[i], d));
    if (l15 == 0)
#pragma unroll
        for (int i = 0; i < 2; i++)
#pragma unroll
            for (int r = 0; r < 4; r++)
                mpart[w][i * 16 + quad * 4 + r] = mx[i * 4 + r];
    __syncthreads();
    if (t < 32)
        mrow[t] = fmaxf(fmaxf(mpart[0][t], mpart[1][t]),
                        fmaxf(mpart[2][t], mpart[3][t]));
    __syncthreads();

    // ====== exp in place (bf16) + row sums; row r owned by one lane-octet =
    {
        int r = t >> 3, seg = t & 7;
        float mr = mrow[r];
        float sum = 0.f;
#pragma unroll 4
        for (int i = 0; i < 16; i++) {
            int u = i * 8 + seg;   // consecutive lanes -> distinct unit class
            short8 v = *(const short8*)&S[r * TS + u * 8];
            short8 o;
#pragma unroll
            for (int e = 0; e < 8; e++) {
                float f = __expf(bf2f(v[e]) - mr);
                o[e] = f2bf(f);
                sum += f;
            }
            *(short8*)&S[r * TS + u * 8] = o;
        }
        sum += __shfl_xor(sum, 1);
        sum += __shfl_xor(sum, 2);
        sum += __shfl_xor(sum, 4);
        if (seg == 0) lrow[r] = sum;
    }
    __syncthreads();

    // ====== probs: normalized fp32, one full row per iteration ============
#pragma unroll 2
    for (int r = 0; r < 32; r++) {
        float inv = 1.0f / lrow[r];
        short4 v = *(const short4*)&S[r * TS + t * 4];
        float4 o;
        o.x = bf2f(v.x) * inv; o.y = bf2f(v.y) * inv;
        o.z = bf2f(v.z) * inv; o.w = bf2f(v.w) * inv;
        ((float4*)(Pg + (size_t)r * LK))[t] = o;
    }

    // ====== PV: barrier-free; A-frags are bf16 S rows, B-frags from L2 ====
    int wr = w >> 1, wc = w & 1;
    floatx4 accO[2] = {};
#pragma unroll 4
    for (int kc = 0; kc < 16; kc++) {
        short8 pa[2];
#pragma unroll
        for (int ks = 0; ks < 2; ks++)
            pa[ks] = *(const short8*)&S[(wr * 16 + l15) * TS
                                        + kc * 64 + ks * 32 + quad * 8];
#pragma unroll
        for (int ks = 0; ks < 2; ks++)
#pragma unroll
            for (int j = 0; j < 2; j++) {
                int n = wc * 32 + j * 16 + l15;
                short8 bfr = *(const short8*)&Vg[(size_t)n * LK
                                                 + kc * 64 + ks * 32 + quad * 8];
                accO[j] = __builtin_amdgcn_mfma_f32_16x16x32_bf16(
                    pa[ks], bfr, accO[j], 0, 0, 0);
            }
    }

    // ctx epilogue: rescale by 1/l, bf16 out
    float inv[4];
#pragma unroll
    for (int r = 0; r < 4; r++) inv[r] = 1.0f / lrow[wr * 16 + quad * 4 + r];
#pragma unroll
    for (int j = 0; j < 2; j++) {
        int n = wc * 32 + j * 16 + l15;
#pragma unroll
        for (int r = 0; r < 4; r++) {
            int m = wr * 16 + quad * 4 + r;
            Cg[(size_t)m * HIDDEN + n] = f2bf(accO[j][r] * inv[r]);
        }
    }
}

// ---------------------------------------------------------------------------
// Row LayerNorm over HIDDEN=768; one block per row.
// ---------------------------------------------------------------------------
__global__ __launch_bounds__(256)
void layernorm_rows(const float* __restrict__ H, const float* __restrict__ gamma,
                    const float* __restrict__ beta, float* __restrict__ out)
{
    int row = blockIdx.x;
    const float* h = H + (long)row * HIDDEN;
    int t = threadIdx.x;

    float x[3];
    float s = 0.f, ss = 0.f;
#pragma unroll
    for (int i = 0; i < 3; i++) {
        x[i] = h[t + 256 * i];
        s  += x[i];
        ss += x[i] * x[i];
    }
#pragma unroll
    for (int off = 32; off > 0; off >>= 1) {
        s  += __shfl_down(s, off);
        ss += __shfl_down(ss, off);
    }
    __shared__ float sh_s[4], sh_ss[4];
    int wave = t >> 6;
    if ((t & 63) == 0) { sh_s[wave] = s; sh_ss[wave] = ss; }
    __syncthreads();
    float S  = sh_s[0] + sh_s[1] + sh_s[2] + sh_s[3];
    float SS = sh_ss[0] + sh_ss[1] + sh_ss[2] + sh_ss[3];

    float mu  = S * (1.0f / HIDDEN);
    float var = SS * (1.0f / HIDDEN) - mu * mu;
    float inv = rsqrtf(var + LN_EPS);

    float* o = out + (long)row * HIDDEN;
#pragma unroll
    for (int i = 0; i < 3; i++) {
        int c = t + 256 * i;
        o[c] = (x[i] - mu) * inv * gamma[c] + beta[c];
    }
}

// ---------------------------------------------------------------------------
extern "C" void kernel_launch(void* const* d_in, const int* in_sizes, int n_in,
                              void* d_out, int out_size, void* d_ws, size_t ws_size,
                              hipStream_t stream)
{
    const float* query = (const float*)d_in[0];
    const float* key   = (const float*)d_in[1];
    const float* value = (const float*)d_in[2];
    const float* amask = (const float*)d_in[3];
    const float* Wq    = (const float*)d_in[5];
    const float* bq    = (const float*)d_in[6];
    const float* Wk    = (const float*)d_in[7];
    const float* bk    = (const float*)d_in[8];
    const float* Wv    = (const float*)d_in[9];
    const float* bv    = (const float*)d_in[10];
    const float* Wo    = (const float*)d_in[11];
    const float* bo    = (const float*)d_in[12];
    const float* gamma = (const float*)d_in[13];
    const float* beta  = (const float*)d_in[14];

    short* qx = (short*)d_ws;              // 4096*768  query bf16
    short* kx = qx + (long)4096 * 768;     // 8192*768  key bf16
    short* vx = kx + (long)8192 * 768;     // 8192*768  value bf16
    short* wq = vx + (long)8192 * 768;     // 768*768 x4 weights
    short* wk = wq + (long)768 * 768;
    short* wv = wk + (long)768 * 768;
    short* wo = wv + (long)768 * 768;
    short* qb = wo + (long)768 * 768;      // 4096*768  Q proj
    short* kb = qb + (long)4096 * 768;     // 8192*768  K proj
    short* vb = kb + (long)8192 * 768;     // 8192*768  V proj
    short* ctxb = qx;                      // reuse: qx dead after Q proj
    short* vt   = kx;                      // reuse: kx dead after K proj
    float* hbuf = (float*)vx;              // reuse: vx dead after V proj

    float* out0  = (float*)d_out;
    float* probs = out0 + (long)NB * LQ * HIDDEN;

    cvt_f32_bf16<<<(4096 * 768 / 4 + 255) / 256, 256, 0, stream>>>(query, qx, 4096 * 768 / 4);
    cvt_f32_bf16<<<(8192 * 768 / 4 + 255) / 256, 256, 0, stream>>>(key,   kx, 8192 * 768 / 4);
    cvt_f32_bf16<<<(8192 * 768 / 4 + 255) / 256, 256, 0, stream>>>(value, vx, 8192 * 768 / 4);
    cvt_f32_bf16<<<(768 * 768 / 4 + 255) / 256, 256, 0, stream>>>(Wq, wq, 768 * 768 / 4);
    cvt_f32_bf16<<<(768 * 768 / 4 + 255) / 256, 256, 0, stream>>>(Wk, wk, 768 * 768 / 4);
    cvt_f32_bf16<<<(768 * 768 / 4 + 255) / 256, 256, 0, stream>>>(Wv, wv, 768 * 768 / 4);
    cvt_f32_bf16<<<(768 * 768 / 4 + 255) / 256, 256, 0, stream>>>(Wo, wo, 768 * 768 / 4);

    gemm_nt_mfma<<<dim3(6, 32), 256, 0, stream>>>(
        qx, wq, nullptr, qb, bq, nullptr, HIDDEN, HIDDEN, HIDDEN, HIDDEN, 1.0f);
    gemm_nt_mfma<<<dim3(6, 64), 256, 0, stream>>>(
        kx, wk, nullptr, kb, bk, nullptr, HIDDEN, HIDDEN, HIDDEN, HIDDEN, 1.0f);
    gemm_nt_mfma<<<dim3(6, 64), 256, 0, stream>>>(
        vx, wv, nullptr, vb, bv, nullptr, HIDDEN, HIDDEN, HIDDEN, HIDDEN, 1.0f);

    transpose_v<<<dim3(4, 96), 256, 0, stream>>>(vb, vt);

    fused_attn<<<dim3(16, 96), 256, 0, stream>>>(qb, kb, vt, amask, probs, ctxb);

    gemm_nt_mfma<<<dim3(6, 32), 256, 0, stream>>>(
        ctxb, wo, hbuf, nullptr, bo, query, HIDDEN, HIDDEN, HIDDEN, HIDDEN, 1.0f);

    layernorm_rows<<<NB * LQ, 256, 0, stream>>>(hbuf, gamma, beta, out0);
}